// Round 2
// baseline (80.020 us; speedup 1.0000x reference)
//
#include <hip/hip_runtime.h>
#include <hip/hip_bf16.h>

// TripletLoss B=4096 D=128 fp32. R7: two-dispatch pipeline. Phase2 is folded
// into the main kernel as a last-block finalize:
//   - prep: bf16 convert + row norms + init of key arrays (mpg=0,
//     mng=0xFFFFFFFF) + ticket counter.
//   - main (528 upper-triangle blocks): R6 Gram/mining/fold unchanged, then
//     per-row device-scope atomicMax/atomicMin on order-preserving uint keys
//     (bijective encode of fp32, exact), ticket atomicAdd; ticket==527 block
//     runs the finalize inline (LDS label hist, agent-scope key loads,
//     sqrt/relu, reduce, out[0]).
// Removes one kernel dispatch + the 1 MB pmp/pmn round-trip. Numerics are
// bit-identical to R6 (same mining values, same finalize math).

typedef __attribute__((ext_vector_type(8))) short short8;
typedef __attribute__((ext_vector_type(4))) float f32x4;

#define MARGIN_F 0.3f
#define NEG_BIG -3.4e38f
#define POS_BIG 3.4e38f
// gfx9 waitcnt encoding: vmcnt[3:0]|[15:14], expcnt[6:4], lgkmcnt[11:8]
#define WAITVM(N) __builtin_amdgcn_s_waitcnt(((N)&15)|((((N)>>4)&3)<<14)|(7<<4)|(15<<8))

__device__ __forceinline__ void gl_lds16(const void* g, void* l) {
    __builtin_amdgcn_global_load_lds(
        (const __attribute__((address_space(1))) void*)g,
        (__attribute__((address_space(3))) void*)l, 16, 0, 0);
}

__device__ inline unsigned short f2bf(float x) {
    union { __hip_bfloat16 h; unsigned short u; } c;
    c.h = __float2bfloat16(x);
    return c.u;
}

// order-preserving bijective fp32<->uint key (finite floats): x1<x2 <=> e(x1)<e(x2)
__device__ __forceinline__ unsigned encf(float x) {
    unsigned u = __float_as_uint(x);
    return (u >> 31) ? ~u : (u | 0x80000000u);
}
__device__ __forceinline__ float decf(unsigned k) {
    return (k & 0x80000000u) ? __uint_as_float(k ^ 0x80000000u)
                             : __uint_as_float(~k);
}

// grid 512 x 256: 32 threads/row. bf16 convert + row norms + key-array init.
__global__ __launch_bounds__(256) void tl_prep(const float* __restrict__ E,
                                               unsigned short* __restrict__ Ebf,
                                               float* __restrict__ sqn,
                                               unsigned* __restrict__ mpg,
                                               unsigned* __restrict__ mng,
                                               unsigned* __restrict__ cnt) {
    int t = blockIdx.x * 256 + threadIdx.x;
    if (t < 4096) { mpg[t] = 0u; mng[t] = 0xFFFFFFFFu; }
    if (t == 0) cnt[0] = 0u;
    int row = t >> 5;
    int kq = (t & 31) * 4;
    float4 v = *(const float4*)&E[(size_t)row * 128 + kq];
    float s = fmaf(v.x, v.x, fmaf(v.y, v.y, fmaf(v.z, v.z, v.w * v.w)));
    ushort4 h4;
    h4.x = f2bf(v.x); h4.y = f2bf(v.y); h4.z = f2bf(v.z); h4.w = f2bf(v.w);
    *(ushort4*)&Ebf[(size_t)row * 128 + kq] = h4;
#pragma unroll
    for (int m = 1; m < 32; m <<= 1) s += __shfl_xor(s, m);
    if ((t & 31) == 0) sqn[row] = s;
}

// grid 528 x 256. 4 waves 2x2, wave tile 64x64 = 4x4 MFMA 16x16x32.
// LDS per K-chunk: 128 rows x 64 bf16, chunk c of row r at column c^(r&7).
__global__ __launch_bounds__(256, 2) void tl_main(const unsigned short* __restrict__ Ebf,
                                                  const int* __restrict__ labels,
                                                  const float* __restrict__ sqn,
                                                  unsigned* __restrict__ mpg,
                                                  unsigned* __restrict__ mng,
                                                  unsigned* __restrict__ cnt,
                                                  float* __restrict__ out) {
    union SM {
        struct { unsigned short A[2][128 * 64]; unsigned short B[2][128 * 64]; } s;
        struct { float mp[128][32]; float mn[128][32];
                 float mpc[128][8]; float mnc[128][8]; } f;
        unsigned hist[256];
    };
    __shared__ __align__(16) SM sm;
    __shared__ int lastblk;
    __shared__ float sp[4], sv[4];

    const int tid = threadIdx.x;
    const int l = tid & 63, w = tid >> 6;
    const int wr = w >> 1, wc = w & 1;
    const int q = l >> 4, r16 = l & 15;

    // upper-triangle decode: t -> (bx, by), by >= bx.
    int t = (int)blockIdx.x;
    int bx = (int)((65.0f - sqrtf((float)(4225 - 8 * t))) * 0.5f);
    while (bx * (65 - bx) / 2 > t) --bx;
    while ((bx + 1) * (64 - bx) / 2 <= t) ++bx;
    const int by = bx + (t - bx * (65 - bx) / 2);
    const int i0 = bx * 128, j0 = by * 128;
    const bool diagblk = (bx == by);

    // staging sources: slot s = w*256 + t2*64 + l; row=s>>3; chunk=(s&7)^(row&7)
    const unsigned short* gA[4];
    const unsigned short* gB[4];
#pragma unroll
    for (int t2 = 0; t2 < 4; ++t2) {
        int s = w * 256 + t2 * 64 + l;
        int row = s >> 3, ch = (s & 7) ^ (row & 7);
        gA[t2] = Ebf + (size_t)(i0 + row) * 128 + ch * 8;
        gB[t2] = Ebf + (size_t)(j0 + row) * 128 + ch * 8;
    }

    // prefetch epilogue metadata early (independent of staging)
    int li[4][4], lj[4];
    float si[4][4], sj[4];
#pragma unroll
    for (int ti = 0; ti < 4; ++ti)
#pragma unroll
        for (int p = 0; p < 4; ++p) {
            int ci = i0 + wr * 64 + ti * 16 + q * 4 + p;
            li[ti][p] = labels[ci];
            si[ti][p] = sqn[ci];
        }
#pragma unroll
    for (int tj = 0; tj < 4; ++tj) {
        int cj = j0 + wc * 64 + tj * 16 + r16;
        lj[tj] = labels[cj];
        sj[tj] = sqn[cj];
    }

    // issue all staging: chunk0 (8 loads) then chunk1 (8 loads)
#pragma unroll
    for (int t2 = 0; t2 < 4; ++t2) {
        gl_lds16(gA[t2], &sm.s.A[0][w * 2048 + t2 * 512]);
        gl_lds16(gB[t2], &sm.s.B[0][w * 2048 + t2 * 512]);
    }
#pragma unroll
    for (int t2 = 0; t2 < 4; ++t2) {
        gl_lds16(gA[t2] + 64, &sm.s.A[1][w * 2048 + t2 * 512]);
        gl_lds16(gB[t2] + 64, &sm.s.B[1][w * 2048 + t2 * 512]);
    }

    f32x4 acc[4][4];
#pragma unroll
    for (int ti = 0; ti < 4; ++ti)
#pragma unroll
        for (int tj = 0; tj < 4; ++tj) acc[ti][tj] = (f32x4)0.0f;

#pragma unroll
    for (int kc = 0; kc < 2; ++kc) {
        if (kc == 0) WAITVM(8); else WAITVM(0);
        __builtin_amdgcn_s_barrier();
#pragma unroll
        for (int s = 0; s < 2; ++s) {
            short8 af[4], bf[4];
            const int cA = ((s * 4 + q) ^ (r16 & 7)) * 8;
#pragma unroll
            for (int t2 = 0; t2 < 4; ++t2) {
                af[t2] = *(const short8*)&sm.s.A[kc][(wr * 64 + t2 * 16 + r16) * 64 + cA];
                bf[t2] = *(const short8*)&sm.s.B[kc][(wc * 64 + t2 * 16 + r16) * 64 + cA];
            }
#pragma unroll
            for (int ti = 0; ti < 4; ++ti)
#pragma unroll
                for (int tj = 0; tj < 4; ++tj)
                    acc[ti][tj] = __builtin_amdgcn_mfma_f32_16x16x32_bf16(
                        af[ti], bf[tj], acc[ti][tj], 0, 0, 0);
        }
    }

    // mine both directions from the same accumulators (monotone in d2):
    //   row path (rows i over cols j): vr = sq_j - 2g
    //   col path (rows j over cols i): vc = sq_i - 2g   (skipped on diag)
    float mp[4][4], mn[4][4], mpc[4], mnc[4];
#pragma unroll
    for (int ti = 0; ti < 4; ++ti)
#pragma unroll
        for (int p = 0; p < 4; ++p) { mp[ti][p] = NEG_BIG; mn[ti][p] = POS_BIG; }
#pragma unroll
    for (int tj = 0; tj < 4; ++tj) {
        float cp = NEG_BIG, cn = POS_BIG;
#pragma unroll
        for (int ti = 0; ti < 4; ++ti)
#pragma unroll
            for (int p = 0; p < 4; ++p) {
                float g = acc[ti][tj][p];
                float vr = fmaf(-2.0f, g, sj[tj]);
                float vc = fmaf(-2.0f, g, si[ti][p]);
                bool same = (li[ti][p] == lj[tj]);
                bool self = diagblk &&
                    ((wr * 64 + ti * 16 + q * 4 + p) == (wc * 64 + tj * 16 + r16));
                mp[ti][p] = fmaxf(mp[ti][p], (same && !self) ? vr : NEG_BIG);
                mn[ti][p] = fminf(mn[ti][p], same ? POS_BIG : vr);
                cp = fmaxf(cp, (same && !self) ? vc : NEG_BIG);
                cn = fminf(cn, same ? POS_BIG : vc);
            }
        mpc[tj] = cp;
        mnc[tj] = cn;
    }

    // LDS fold: rows get 32 partials (16 col-lanes x 2 wc waves);
    // cols get 8 partials (4 q-lanes x 2 wr waves)
    __syncthreads();  // all LDS frag reads done before aliasing overwrite
#pragma unroll
    for (int ti = 0; ti < 4; ++ti)
#pragma unroll
        for (int p = 0; p < 4; ++p) {
            int rloc = wr * 64 + ti * 16 + q * 4 + p;
            sm.f.mp[rloc][wc * 16 + r16] = mp[ti][p];
            sm.f.mn[rloc][wc * 16 + r16] = mn[ti][p];
        }
#pragma unroll
    for (int tj = 0; tj < 4; ++tj) {
        int cloc = wc * 64 + tj * 16 + r16;
        sm.f.mpc[cloc][wr * 4 + q] = mpc[tj];
        sm.f.mnc[cloc][wr * 4 + q] = mnc[tj];
    }
    __syncthreads();
    {
        int row = tid >> 1, hf = tid & 1;
        const float4* P = (const float4*)&sm.f.mp[row][hf * 16];
        const float4* N = (const float4*)&sm.f.mn[row][hf * 16];
        float4 p0 = P[0], p1 = P[1], p2 = P[2], p3 = P[3];
        float4 n0 = N[0], n1 = N[1], n2 = N[2], n3 = N[3];
        float M = fmaxf(fmaxf(fmaxf(p0.x, p0.y), fmaxf(p0.z, p0.w)),
                        fmaxf(fmaxf(p1.x, p1.y), fmaxf(p1.z, p1.w)));
        M = fmaxf(M, fmaxf(fmaxf(fmaxf(p2.x, p2.y), fmaxf(p2.z, p2.w)),
                           fmaxf(fmaxf(p3.x, p3.y), fmaxf(p3.z, p3.w))));
        float m_ = fminf(fminf(fminf(n0.x, n0.y), fminf(n0.z, n0.w)),
                         fminf(fminf(n1.x, n1.y), fminf(n1.z, n1.w)));
        m_ = fminf(m_, fminf(fminf(fminf(n2.x, n2.y), fminf(n2.z, n2.w)),
                             fminf(fminf(n3.x, n3.y), fminf(n3.z, n3.w))));
        M = fmaxf(M, __shfl_xor(M, 1));
        m_ = fminf(m_, __shfl_xor(m_, 1));
        if (hf == 0) {
            atomicMax(&mpg[i0 + row], encf(M));
            atomicMin(&mng[i0 + row], encf(m_));
        }
    }
    // transposed path: rows j of block by, reduced over cols i
    if (!diagblk && tid < 128) {
        const float4* P = (const float4*)&sm.f.mpc[tid][0];
        const float4* N = (const float4*)&sm.f.mnc[tid][0];
        float4 p0 = P[0], p1 = P[1];
        float4 n0 = N[0], n1 = N[1];
        float M = fmaxf(fmaxf(fmaxf(p0.x, p0.y), fmaxf(p0.z, p0.w)),
                        fmaxf(fmaxf(p1.x, p1.y), fmaxf(p1.z, p1.w)));
        float m_ = fminf(fminf(fminf(n0.x, n0.y), fminf(n0.z, n0.w)),
                         fminf(fminf(n1.x, n1.y), fminf(n1.z, n1.w)));
        atomicMax(&mpg[j0 + tid], encf(M));
        atomicMin(&mng[j0 + tid], encf(m_));
    }

    // ticket: the last block to finish runs the finalize inline.
    __syncthreads();  // all this block's atomics drained (vmcnt(0) at barrier)
    if (tid == 0) {
        __threadfence();
        lastblk = (atomicAdd(cnt, 1u) == 527u);
    }
    __syncthreads();
    if (!lastblk) return;
    __threadfence();

    // finalize == old phase2, on the dead staging LDS.
    sm.hist[tid] = 0u;
    __syncthreads();
    int lab[16];
#pragma unroll
    for (int k = 0; k < 16; ++k) {
        lab[k] = labels[k * 256 + tid];
        atomicAdd(&sm.hist[lab[k]], 1u);
    }
    __syncthreads();
    float s = 0.0f, n = 0.0f;
#pragma unroll
    for (int k = 0; k < 16; ++k) {
        int r = k * 256 + tid;
        unsigned kp = __hip_atomic_load(&mpg[r], __ATOMIC_RELAXED, __HIP_MEMORY_SCOPE_AGENT);
        unsigned kn = __hip_atomic_load(&mng[r], __ATOMIC_RELAXED, __HIP_MEMORY_SCOPE_AGENT);
        float mpv = decf(kp), mnv = decf(kn);
        float sir = sqn[r];
        unsigned c = sm.hist[lab[k]];
        bool valid = (c >= 2u) && (c < 4096u);
        float hp = sqrtf(fmaxf(sir + mpv, 0.0f));
        float hn = sqrtf(fmaxf(sir + mnv, 0.0f));
        float pr = fmaxf(hp - hn + MARGIN_F, 0.0f);
        if (valid) { s += pr; n += 1.0f; }
    }
#pragma unroll
    for (int m = 1; m < 64; m <<= 1) {
        s += __shfl_xor(s, m);
        n += __shfl_xor(n, m);
    }
    if ((tid & 63) == 0) { sp[tid >> 6] = s; sv[tid >> 6] = n; }
    __syncthreads();
    if (tid == 0) {
        float ts = sp[0] + sp[1] + sp[2] + sp[3];
        float tn = sv[0] + sv[1] + sv[2] + sv[3];
        out[0] = ts / fmaxf(tn, 1.0f);
    }
}

extern "C" void kernel_launch(void* const* d_in, const int* in_sizes, int n_in,
                              void* d_out, int out_size, void* d_ws, size_t ws_size,
                              hipStream_t stream) {
    const float* E = (const float*)d_in[0];
    const int* labels = (const int*)d_in[1];
    float* out = (float*)d_out;

    // ws: mpg 16K | mng 16K | sqn 16K | cnt | Ebf 1MB @64K
    char* base = (char*)d_ws;
    unsigned* mpg = (unsigned*)base;
    unsigned* mng = (unsigned*)(base + (16u << 10));
    float* sqn = (float*)(base + (32u << 10));
    unsigned* cnt = (unsigned*)(base + (48u << 10));
    unsigned short* Ebf = (unsigned short*)(base + (64u << 10));

    tl_prep<<<512, 256, 0, stream>>>(E, Ebf, sqn, mpg, mng, cnt);
    tl_main<<<528, 256, 0, stream>>>(Ebf, labels, sqn, mpg, mng, cnt, out);
}

// Round 3
// 79.609 us; speedup vs baseline: 1.0052x; 1.0052x over previous
//
#include <hip/hip_runtime.h>
#include <hip/hip_bf16.h>

// TripletLoss B=4096 D=128 fp32. R8: single-round main + in-kernel finalize.
//  - Staging: single 32 KB buffer, 2-phase (K-chunk 0 compute, reload, chunk 1)
//    -> LDS 40 KB union -> 3 blocks/CU (768 slots >= 528 blocks = ONE round;
//    R5~R6 showed the 2-block/CU straggler round ate the triangle savings).
//  - launch_bounds(256,3); epilogue metadata loads moved AFTER the K-loop to
//    keep MFMA-section VGPRs under the 3-wave/EU cap.
//  - Phase2 folded in: R6's atomic-free partial stores kept verbatim; each
//    block draws ONE release-scoped ticket; tickets 512..527 spin (ACQUIRE)
//    until all 528 done, then each runs one phase2-block's work (pmp/pmn via
//    relaxed agent atomic loads), accum + ticket2 writes out[0].
// NOT R7's scheme: no per-element atomic storm, no single-block finalize.

typedef __attribute__((ext_vector_type(8))) short short8;
typedef __attribute__((ext_vector_type(4))) float f32x4;

#define MARGIN_F 0.3f
#define NEG_BIG -3.4e38f
#define POS_BIG 3.4e38f
// gfx9 waitcnt encoding: vmcnt[3:0]|[15:14], expcnt[6:4], lgkmcnt[11:8]
#define WAITVM(N) __builtin_amdgcn_s_waitcnt(((N)&15)|((((N)>>4)&3)<<14)|(7<<4)|(15<<8))

__device__ __forceinline__ void gl_lds16(const void* g, void* l) {
    __builtin_amdgcn_global_load_lds(
        (const __attribute__((address_space(1))) void*)g,
        (__attribute__((address_space(3))) void*)l, 16, 0, 0);
}

__device__ inline unsigned short f2bf(float x) {
    union { __hip_bfloat16 h; unsigned short u; } c;
    c.h = __float2bfloat16(x);
    return c.u;
}

// grid 512 x 256: 32 threads/row. bf16 convert + row norms + counter zero.
__global__ __launch_bounds__(256) void tl_prep(const float* __restrict__ E,
                                               unsigned short* __restrict__ Ebf,
                                               float* __restrict__ sqn,
                                               unsigned* __restrict__ accum) {
    int t = blockIdx.x * 256 + threadIdx.x;
    if (t < 4) accum[t] = 0u;
    int row = t >> 5;
    int kq = (t & 31) * 4;
    float4 v = *(const float4*)&E[(size_t)row * 128 + kq];
    float s = fmaf(v.x, v.x, fmaf(v.y, v.y, fmaf(v.z, v.z, v.w * v.w)));
    ushort4 h4;
    h4.x = f2bf(v.x); h4.y = f2bf(v.y); h4.z = f2bf(v.z); h4.w = f2bf(v.w);
    *(ushort4*)&Ebf[(size_t)row * 128 + kq] = h4;
#pragma unroll
    for (int m = 1; m < 32; m <<= 1) s += __shfl_xor(s, m);
    if ((t & 31) == 0) sqn[row] = s;
}

// grid 528 x 256. 4 waves 2x2, wave tile 64x64 = 4x4 MFMA 16x16x32.
// LDS per K-chunk: 128 rows x 64 bf16, chunk c of row r at column c^(r&7).
__global__ __launch_bounds__(256, 3) void tl_main(const unsigned short* __restrict__ Ebf,
                                                  const int* __restrict__ labels,
                                                  const float* __restrict__ sqn,
                                                  float* __restrict__ pmp,
                                                  float* __restrict__ pmn,
                                                  unsigned* __restrict__ cnt,
                                                  float* __restrict__ accum,
                                                  float* __restrict__ out) {
    union SM {
        struct { unsigned short A[128 * 64]; unsigned short B[128 * 64]; } s;  // 32 KB
        struct { float mp[128][32]; float mn[128][32];
                 float mpc[128][8]; float mnc[128][8]; } f;                    // 40 KB
        unsigned hist[256];
    };
    __shared__ __align__(16) SM sm;
    __shared__ unsigned myticket;
    __shared__ float sp[4], sv[4];

    const int tid = threadIdx.x;
    const int l = tid & 63, w = tid >> 6;
    const int wr = w >> 1, wc = w & 1;
    const int q = l >> 4, r16 = l & 15;

    // upper-triangle decode: t -> (bx, by), by >= bx.
    int t = (int)blockIdx.x;
    int bx = (int)((65.0f - sqrtf((float)(4225 - 8 * t))) * 0.5f);
    while (bx * (65 - bx) / 2 > t) --bx;
    while ((bx + 1) * (64 - bx) / 2 <= t) ++bx;
    const int by = bx + (t - bx * (65 - bx) / 2);
    const int i0 = bx * 128, j0 = by * 128;
    const bool diagblk = (bx == by);

    // staging sources: slot s = w*256 + t2*64 + l; row=s>>3; chunk=(s&7)^(row&7)
    const unsigned short* gA[4];
    const unsigned short* gB[4];
#pragma unroll
    for (int t2 = 0; t2 < 4; ++t2) {
        int s = w * 256 + t2 * 64 + l;
        int row = s >> 3, ch = (s & 7) ^ (row & 7);
        gA[t2] = Ebf + (size_t)(i0 + row) * 128 + ch * 8;
        gB[t2] = Ebf + (size_t)(j0 + row) * 128 + ch * 8;
    }

    f32x4 acc[4][4];
#pragma unroll
    for (int ti = 0; ti < 4; ++ti)
#pragma unroll
        for (int tj = 0; tj < 4; ++tj) acc[ti][tj] = (f32x4)0.0f;

    // phase kc=0 issue (8 gl_lds16/thread)
#pragma unroll
    for (int t2 = 0; t2 < 4; ++t2) {
        gl_lds16(gA[t2], &sm.s.A[w * 2048 + t2 * 512]);
        gl_lds16(gB[t2], &sm.s.B[w * 2048 + t2 * 512]);
    }

#pragma unroll
    for (int kc = 0; kc < 2; ++kc) {
        if (kc == 1) {
            __syncthreads();  // all ds_reads of chunk0 done before overwrite
#pragma unroll
            for (int t2 = 0; t2 < 4; ++t2) {
                gl_lds16(gA[t2] + 64, &sm.s.A[w * 2048 + t2 * 512]);
                gl_lds16(gB[t2] + 64, &sm.s.B[w * 2048 + t2 * 512]);
            }
        }
        WAITVM(0);
        __builtin_amdgcn_s_barrier();
#pragma unroll
        for (int s = 0; s < 2; ++s) {
            short8 af[4], bf[4];
            const int cA = ((s * 4 + q) ^ (r16 & 7)) * 8;
#pragma unroll
            for (int t2 = 0; t2 < 4; ++t2) {
                af[t2] = *(const short8*)&sm.s.A[(wr * 64 + t2 * 16 + r16) * 64 + cA];
                bf[t2] = *(const short8*)&sm.s.B[(wc * 64 + t2 * 16 + r16) * 64 + cA];
            }
#pragma unroll
            for (int ti = 0; ti < 4; ++ti)
#pragma unroll
                for (int tj = 0; tj < 4; ++tj)
                    acc[ti][tj] = __builtin_amdgcn_mfma_f32_16x16x32_bf16(
                        af[ti], bf[tj], acc[ti][tj], 0, 0, 0);
        }
    }

    // epilogue metadata AFTER the K-loop (keeps MFMA-section VGPRs low)
    int li[4][4], lj[4];
    float si[4][4], sj[4];
#pragma unroll
    for (int ti = 0; ti < 4; ++ti)
#pragma unroll
        for (int p = 0; p < 4; ++p) {
            int ci = i0 + wr * 64 + ti * 16 + q * 4 + p;
            li[ti][p] = labels[ci];
            si[ti][p] = sqn[ci];
        }
#pragma unroll
    for (int tj = 0; tj < 4; ++tj) {
        int cj = j0 + wc * 64 + tj * 16 + r16;
        lj[tj] = labels[cj];
        sj[tj] = sqn[cj];
    }

    // mine both directions (monotone in d2): row path vr = sq_j - 2g -> slot by;
    // col path vc = sq_i - 2g -> slot bx (skipped on diag).
    float mp[4][4], mn[4][4], mpc[4], mnc[4];
#pragma unroll
    for (int ti = 0; ti < 4; ++ti)
#pragma unroll
        for (int p = 0; p < 4; ++p) { mp[ti][p] = NEG_BIG; mn[ti][p] = POS_BIG; }
#pragma unroll
    for (int tj = 0; tj < 4; ++tj) {
        float cp = NEG_BIG, cn = POS_BIG;
#pragma unroll
        for (int ti = 0; ti < 4; ++ti)
#pragma unroll
            for (int p = 0; p < 4; ++p) {
                float g = acc[ti][tj][p];
                float vr = fmaf(-2.0f, g, sj[tj]);
                float vc = fmaf(-2.0f, g, si[ti][p]);
                bool same = (li[ti][p] == lj[tj]);
                bool self = diagblk &&
                    ((wr * 64 + ti * 16 + q * 4 + p) == (wc * 64 + tj * 16 + r16));
                mp[ti][p] = fmaxf(mp[ti][p], (same && !self) ? vr : NEG_BIG);
                mn[ti][p] = fminf(mn[ti][p], same ? POS_BIG : vr);
                cp = fmaxf(cp, (same && !self) ? vc : NEG_BIG);
                cn = fminf(cn, same ? POS_BIG : vc);
            }
        mpc[tj] = cp;
        mnc[tj] = cn;
    }

    // LDS fold: rows get 32 partials (16 col-lanes x 2 wc waves);
    // cols get 8 partials (4 q-lanes x 2 wr waves)
    __syncthreads();  // all LDS frag reads done before aliasing overwrite
#pragma unroll
    for (int ti = 0; ti < 4; ++ti)
#pragma unroll
        for (int p = 0; p < 4; ++p) {
            int rloc = wr * 64 + ti * 16 + q * 4 + p;
            sm.f.mp[rloc][wc * 16 + r16] = mp[ti][p];
            sm.f.mn[rloc][wc * 16 + r16] = mn[ti][p];
        }
#pragma unroll
    for (int tj = 0; tj < 4; ++tj) {
        int cloc = wc * 64 + tj * 16 + r16;
        sm.f.mpc[cloc][wr * 4 + q] = mpc[tj];
        sm.f.mnc[cloc][wr * 4 + q] = mnc[tj];
    }
    __syncthreads();
    {
        int row = tid >> 1, hf = tid & 1;
        const float4* P = (const float4*)&sm.f.mp[row][hf * 16];
        const float4* N = (const float4*)&sm.f.mn[row][hf * 16];
        float4 p0 = P[0], p1 = P[1], p2 = P[2], p3 = P[3];
        float4 n0 = N[0], n1 = N[1], n2 = N[2], n3 = N[3];
        float M = fmaxf(fmaxf(fmaxf(p0.x, p0.y), fmaxf(p0.z, p0.w)),
                        fmaxf(fmaxf(p1.x, p1.y), fmaxf(p1.z, p1.w)));
        M = fmaxf(M, fmaxf(fmaxf(fmaxf(p2.x, p2.y), fmaxf(p2.z, p2.w)),
                           fmaxf(fmaxf(p3.x, p3.y), fmaxf(p3.z, p3.w))));
        float m_ = fminf(fminf(fminf(n0.x, n0.y), fminf(n0.z, n0.w)),
                         fminf(fminf(n1.x, n1.y), fminf(n1.z, n1.w)));
        m_ = fminf(m_, fminf(fminf(fminf(n2.x, n2.y), fminf(n2.z, n2.w)),
                             fminf(fminf(n3.x, n3.y), fminf(n3.z, n3.w))));
        M = fmaxf(M, __shfl_xor(M, 1));
        m_ = fminf(m_, __shfl_xor(m_, 1));
        if (hf == 0) {
            pmp[(size_t)by * 4096 + i0 + row] = M;
            pmn[(size_t)by * 4096 + i0 + row] = m_;
        }
    }
    // transposed store: rows j of block by, reduced over cols i -> slot bx
    if (!diagblk && tid < 128) {
        const float4* P = (const float4*)&sm.f.mpc[tid][0];
        const float4* N = (const float4*)&sm.f.mnc[tid][0];
        float4 p0 = P[0], p1 = P[1];
        float4 n0 = N[0], n1 = N[1];
        float M = fmaxf(fmaxf(fmaxf(p0.x, p0.y), fmaxf(p0.z, p0.w)),
                        fmaxf(fmaxf(p1.x, p1.y), fmaxf(p1.z, p1.w)));
        float m_ = fminf(fminf(fminf(n0.x, n0.y), fminf(n0.z, n0.w)),
                         fminf(fminf(n1.x, n1.y), fminf(n1.z, n1.w)));
        pmp[(size_t)bx * 4096 + j0 + tid] = M;
        pmn[(size_t)bx * 4096 + j0 + tid] = m_;
    }

    // one release-scoped ticket per block; last 16 finalize in parallel.
    __syncthreads();  // drains each thread's global stores before the ticket
    if (tid == 0)
        myticket = __hip_atomic_fetch_add(&cnt[0], 1u, __ATOMIC_RELEASE,
                                          __HIP_MEMORY_SCOPE_AGENT);
    __syncthreads();
    unsigned tk = myticket;
    if (tk < 512u) return;

    if (tid == 0) {
        while (__hip_atomic_load(&cnt[0], __ATOMIC_ACQUIRE,
                                 __HIP_MEMORY_SCOPE_AGENT) < 528u)
            __builtin_amdgcn_s_sleep(8);
    }
    __syncthreads();
    const int slice = (int)(tk - 512u);

    // finalize == old phase2 block, on the dead staging LDS.
    sm.hist[tid] = 0u;
    __syncthreads();
#pragma unroll
    for (int k = 0; k < 16; ++k) atomicAdd(&sm.hist[labels[k * 256 + tid]], 1u);
    __syncthreads();

    int r = slice * 256 + tid;
    float fmp = NEG_BIG, fmn = POS_BIG;
#pragma unroll
    for (int k = 0; k < 32; ++k) {
        float vp = __hip_atomic_load(&pmp[(size_t)k * 4096 + r], __ATOMIC_RELAXED,
                                     __HIP_MEMORY_SCOPE_AGENT);
        float vn = __hip_atomic_load(&pmn[(size_t)k * 4096 + r], __ATOMIC_RELAXED,
                                     __HIP_MEMORY_SCOPE_AGENT);
        fmp = fmaxf(fmp, vp);
        fmn = fminf(fmn, vn);
    }
    float sir = sqn[r];
    unsigned c = sm.hist[labels[r]];
    bool valid = (c >= 2u) && (c < 4096u);
    float hp = sqrtf(fmaxf(sir + fmp, 0.0f));
    float hn = sqrtf(fmaxf(sir + fmn, 0.0f));
    float pr = fmaxf(hp - hn + MARGIN_F, 0.0f);
    float s = valid ? pr : 0.0f;
    float n = valid ? 1.0f : 0.0f;
#pragma unroll
    for (int m = 1; m < 64; m <<= 1) {
        s += __shfl_xor(s, m);
        n += __shfl_xor(n, m);
    }
    if ((tid & 63) == 0) { sp[tid >> 6] = s; sv[tid >> 6] = n; }
    __syncthreads();
    if (tid == 0) {
        float ts = sp[0] + sp[1] + sp[2] + sp[3];
        float tn = sv[0] + sv[1] + sv[2] + sv[3];
        __hip_atomic_fetch_add(&accum[0], ts, __ATOMIC_RELAXED, __HIP_MEMORY_SCOPE_AGENT);
        __hip_atomic_fetch_add(&accum[1], tn, __ATOMIC_RELAXED, __HIP_MEMORY_SCOPE_AGENT);
        unsigned tk2 = __hip_atomic_fetch_add(&cnt[1], 1u, __ATOMIC_ACQ_REL,
                                              __HIP_MEMORY_SCOPE_AGENT);
        if (tk2 == 15u) {
            float a = __hip_atomic_load(&accum[0], __ATOMIC_RELAXED, __HIP_MEMORY_SCOPE_AGENT);
            float b = __hip_atomic_load(&accum[1], __ATOMIC_RELAXED, __HIP_MEMORY_SCOPE_AGENT);
            out[0] = a / fmaxf(b, 1.0f);
        }
    }
}

extern "C" void kernel_launch(void* const* d_in, const int* in_sizes, int n_in,
                              void* d_out, int out_size, void* d_ws, size_t ws_size,
                              hipStream_t stream) {
    const float* E = (const float*)d_in[0];
    const int* labels = (const int*)d_in[1];
    float* out = (float*)d_out;

    // ws: Ebf 1 MB | pmp 512 KB | pmn 512 KB | sqn 16 KB | accum[0..1] f32 + cnt[0..1] u32
    char* base = (char*)d_ws;
    unsigned short* Ebf = (unsigned short*)base;
    float* pmp = (float*)(base + (1u << 20));
    float* pmn = (float*)(base + (1u << 20) + (512u << 10));
    float* sqn = (float*)(base + (2u << 20));
    float* accum = (float*)(base + (2u << 20) + (16u << 10));
    unsigned* cnt = (unsigned*)(accum + 2);

    tl_prep<<<512, 256, 0, stream>>>(E, Ebf, sqn, (unsigned*)accum);
    tl_main<<<528, 256, 0, stream>>>(Ebf, labels, sqn, pmp, pmn, cnt, accum, out);
}

// Round 4
// 72.466 us; speedup vs baseline: 1.1042x; 1.0986x over previous
//
#include <hip/hip_runtime.h>
#include <hip/hip_bf16.h>

// TripletLoss B=4096 D=128 fp32. R9 = R6 structure (best: 72.2us) + one-round
// phase1. Diagonal tiles are folded into off-diagonal hosts:
//   - grid 496 (= 32*31/2 off-diag blocks) <= 512 slots @2 blocks/CU -> ONE
//     scheduling round (R6's 528 needed a 2nd round for 16 stragglers).
//   - block (d,d+1) computes diag(d) from its already-staged A panel;
//     block (0,31) computes diag(31) from its B panel. No extra staging;
//     +64 MFMA/wave on the 32 host blocks only. Diag row-partials go to the
//     now-orphaned slot d of row-block d (coverage stays exact, single-writer).
//   - li/si epilogue loads vectorized (int4/float4).
// R7/R8 lesson: do NOT merge phase2 into main (both attempts +7.4us).

typedef __attribute__((ext_vector_type(8))) short short8;
typedef __attribute__((ext_vector_type(4))) float f32x4;

#define MARGIN_F 0.3f
#define NEG_BIG -3.4e38f
#define POS_BIG 3.4e38f
// gfx9 waitcnt encoding: vmcnt[3:0]|[15:14], expcnt[6:4], lgkmcnt[11:8]
#define WAITVM(N) __builtin_amdgcn_s_waitcnt(((N)&15)|((((N)>>4)&3)<<14)|(7<<4)|(15<<8))

__device__ __forceinline__ void gl_lds16(const void* g, void* l) {
    __builtin_amdgcn_global_load_lds(
        (const __attribute__((address_space(1))) void*)g,
        (__attribute__((address_space(3))) void*)l, 16, 0, 0);
}

__device__ inline unsigned short f2bf(float x) {
    union { __hip_bfloat16 h; unsigned short u; } c;
    c.h = __float2bfloat16(x);
    return c.u;
}

// grid 512 x 256: 32 threads/row. bf16 convert + row norms + zero accum.
__global__ __launch_bounds__(256) void tl_prep(const float* __restrict__ E,
                                               unsigned short* __restrict__ Ebf,
                                               float* __restrict__ sqn,
                                               unsigned* __restrict__ accum) {
    int t = blockIdx.x * 256 + threadIdx.x;
    if (t < 4) accum[t] = 0u;
    int row = t >> 5;
    int kq = (t & 31) * 4;
    float4 v = *(const float4*)&E[(size_t)row * 128 + kq];
    float s = fmaf(v.x, v.x, fmaf(v.y, v.y, fmaf(v.z, v.z, v.w * v.w)));
    ushort4 h4;
    h4.x = f2bf(v.x); h4.y = f2bf(v.y); h4.z = f2bf(v.z); h4.w = f2bf(v.w);
    *(ushort4*)&Ebf[(size_t)row * 128 + kq] = h4;
#pragma unroll
    for (int m = 1; m < 32; m <<= 1) s += __shfl_xor(s, m);
    if ((t & 31) == 0) sqn[row] = s;
}

// grid 496 x 256. 4 waves 2x2, wave tile 64x64 = 4x4 MFMA 16x16x32.
// LDS per K-chunk: 128 rows x 64 bf16, chunk c of row r at column c^(r&7).
__global__ __launch_bounds__(256, 2) void tl_phase1(const unsigned short* __restrict__ Ebf,
                                                    const int* __restrict__ labels,
                                                    const float* __restrict__ sqn,
                                                    float* __restrict__ pmp,
                                                    float* __restrict__ pmn) {
    union SM {
        struct { unsigned short A[2][128 * 64]; unsigned short B[2][128 * 64]; } s;
        struct { float mp[128][32]; float mn[128][32];
                 float mpc[128][8]; float mnc[128][8]; } f;
    };
    __shared__ __align__(16) SM sm;

    const int tid = threadIdx.x;
    const int l = tid & 63, w = tid >> 6;
    const int wr = w >> 1, wc = w & 1;
    const int q = l >> 4, r16 = l & 15;

    // strict-upper-triangle decode: t -> (bx, by), by > bx, nb=32.
    // start(bx) = bx*(63-bx)/2
    int t = (int)blockIdx.x;
    int bx = (int)((63.0f - sqrtf((float)(3969 - 8 * t))) * 0.5f);
    while (bx * (63 - bx) / 2 > t) --bx;
    while ((bx + 1) * (62 - bx) / 2 <= t) ++bx;
    const int by = bx + 1 + (t - bx * (63 - bx) / 2);
    const int i0 = bx * 128, j0 = by * 128;

    // diag hosting: (d,d+1) hosts diag(d) from A panel; (0,31) hosts diag(31)
    // from B panel.
    const bool hostA = (by == bx + 1);
    const bool hostB = (bx == 0) && (by == 31);
    const bool hasdiag = hostA || hostB;
    const int dbase = hostA ? i0 : j0;   // panel row base of the hosted diag
    const int dslot = hostA ? bx : by;   // partial slot for the hosted diag

    // staging sources: slot s = w*256 + t2*64 + l; row=s>>3; chunk=(s&7)^(row&7)
    const unsigned short* gA[4];
    const unsigned short* gB[4];
#pragma unroll
    for (int t2 = 0; t2 < 4; ++t2) {
        int s = w * 256 + t2 * 64 + l;
        int row = s >> 3, ch = (s & 7) ^ (row & 7);
        gA[t2] = Ebf + (size_t)(i0 + row) * 128 + ch * 8;
        gB[t2] = Ebf + (size_t)(j0 + row) * 128 + ch * 8;
    }

    // prefetch epilogue metadata early (independent of staging)
    int li[4][4], lj[4];
    float si[4][4], sj[4];
#pragma unroll
    for (int ti = 0; ti < 4; ++ti) {
        int cb = i0 + wr * 64 + ti * 16 + q * 4;
        int4 lv = *(const int4*)&labels[cb];
        float4 sv = *(const float4*)&sqn[cb];
        li[ti][0] = lv.x; li[ti][1] = lv.y; li[ti][2] = lv.z; li[ti][3] = lv.w;
        si[ti][0] = sv.x; si[ti][1] = sv.y; si[ti][2] = sv.z; si[ti][3] = sv.w;
    }
#pragma unroll
    for (int tj = 0; tj < 4; ++tj) {
        int cj = j0 + wc * 64 + tj * 16 + r16;
        lj[tj] = labels[cj];
        sj[tj] = sqn[cj];
    }

    // issue all staging: chunk0 (8 loads) then chunk1 (8 loads)
#pragma unroll
    for (int t2 = 0; t2 < 4; ++t2) {
        gl_lds16(gA[t2], &sm.s.A[0][w * 2048 + t2 * 512]);
        gl_lds16(gB[t2], &sm.s.B[0][w * 2048 + t2 * 512]);
    }
#pragma unroll
    for (int t2 = 0; t2 < 4; ++t2) {
        gl_lds16(gA[t2] + 64, &sm.s.A[1][w * 2048 + t2 * 512]);
        gl_lds16(gB[t2] + 64, &sm.s.B[1][w * 2048 + t2 * 512]);
    }

    f32x4 acc[4][4], accd[4][4];
#pragma unroll
    for (int ti = 0; ti < 4; ++ti)
#pragma unroll
        for (int tj = 0; tj < 4; ++tj) acc[ti][tj] = (f32x4)0.0f;
    if (hasdiag) {
#pragma unroll
        for (int ti = 0; ti < 4; ++ti)
#pragma unroll
            for (int tj = 0; tj < 4; ++tj) accd[ti][tj] = (f32x4)0.0f;
    }

#pragma unroll
    for (int kc = 0; kc < 2; ++kc) {
        if (kc == 0) WAITVM(8); else WAITVM(0);
        __builtin_amdgcn_s_barrier();
        const unsigned short* Dk = hostA ? &sm.s.A[kc][0] : &sm.s.B[kc][0];
#pragma unroll
        for (int s = 0; s < 2; ++s) {
            short8 af[4], bf[4];
            const int cA = ((s * 4 + q) ^ (r16 & 7)) * 8;
#pragma unroll
            for (int t2 = 0; t2 < 4; ++t2) {
                af[t2] = *(const short8*)&sm.s.A[kc][(wr * 64 + t2 * 16 + r16) * 64 + cA];
                bf[t2] = *(const short8*)&sm.s.B[kc][(wc * 64 + t2 * 16 + r16) * 64 + cA];
            }
#pragma unroll
            for (int ti = 0; ti < 4; ++ti)
#pragma unroll
                for (int tj = 0; tj < 4; ++tj)
                    acc[ti][tj] = __builtin_amdgcn_mfma_f32_16x16x32_bf16(
                        af[ti], bf[tj], acc[ti][tj], 0, 0, 0);
            if (hasdiag) {
                short8 dA[4], dB[4];
#pragma unroll
                for (int t2 = 0; t2 < 4; ++t2) {
                    dA[t2] = *(const short8*)&Dk[(wr * 64 + t2 * 16 + r16) * 64 + cA];
                    dB[t2] = *(const short8*)&Dk[(wc * 64 + t2 * 16 + r16) * 64 + cA];
                }
#pragma unroll
                for (int ti = 0; ti < 4; ++ti)
#pragma unroll
                    for (int tj = 0; tj < 4; ++tj)
                        accd[ti][tj] = __builtin_amdgcn_mfma_f32_16x16x32_bf16(
                            dA[ti], dB[tj], accd[ti][tj], 0, 0, 0);
            }
        }
    }

    // mine both directions from the same accumulators (monotone in d2):
    //   row path (rows i over cols j): vr = sq_j - 2g -> slot by
    //   col path (rows j over cols i): vc = sq_i - 2g -> slot bx
    // (bx < by strictly, so no self pairs in the off-diag tile)
    float mp[4][4], mn[4][4], mpc[4], mnc[4];
#pragma unroll
    for (int ti = 0; ti < 4; ++ti)
#pragma unroll
        for (int p = 0; p < 4; ++p) { mp[ti][p] = NEG_BIG; mn[ti][p] = POS_BIG; }
#pragma unroll
    for (int tj = 0; tj < 4; ++tj) {
        float cp = NEG_BIG, cn = POS_BIG;
#pragma unroll
        for (int ti = 0; ti < 4; ++ti)
#pragma unroll
            for (int p = 0; p < 4; ++p) {
                float g = acc[ti][tj][p];
                float vr = fmaf(-2.0f, g, sj[tj]);
                float vc = fmaf(-2.0f, g, si[ti][p]);
                bool same = (li[ti][p] == lj[tj]);
                mp[ti][p] = fmaxf(mp[ti][p], same ? vr : NEG_BIG);
                mn[ti][p] = fminf(mn[ti][p], same ? POS_BIG : vr);
                cp = fmaxf(cp, same ? vc : NEG_BIG);
                cn = fminf(cn, same ? POS_BIG : vc);
            }
        mpc[tj] = cp;
        mnc[tj] = cn;
    }

    // LDS fold: rows get 32 partials (16 col-lanes x 2 wc waves);
    // cols get 8 partials (4 q-lanes x 2 wr waves)
    __syncthreads();  // all LDS frag reads done before aliasing overwrite
#pragma unroll
    for (int ti = 0; ti < 4; ++ti)
#pragma unroll
        for (int p = 0; p < 4; ++p) {
            int rloc = wr * 64 + ti * 16 + q * 4 + p;
            sm.f.mp[rloc][wc * 16 + r16] = mp[ti][p];
            sm.f.mn[rloc][wc * 16 + r16] = mn[ti][p];
        }
#pragma unroll
    for (int tj = 0; tj < 4; ++tj) {
        int cloc = wc * 64 + tj * 16 + r16;
        sm.f.mpc[cloc][wr * 4 + q] = mpc[tj];
        sm.f.mnc[cloc][wr * 4 + q] = mnc[tj];
    }
    __syncthreads();
    {
        int row = tid >> 1, hf = tid & 1;
        const float4* P = (const float4*)&sm.f.mp[row][hf * 16];
        const float4* N = (const float4*)&sm.f.mn[row][hf * 16];
        float4 p0 = P[0], p1 = P[1], p2 = P[2], p3 = P[3];
        float4 n0 = N[0], n1 = N[1], n2 = N[2], n3 = N[3];
        float M = fmaxf(fmaxf(fmaxf(p0.x, p0.y), fmaxf(p0.z, p0.w)),
                        fmaxf(fmaxf(p1.x, p1.y), fmaxf(p1.z, p1.w)));
        M = fmaxf(M, fmaxf(fmaxf(fmaxf(p2.x, p2.y), fmaxf(p2.z, p2.w)),
                           fmaxf(fmaxf(p3.x, p3.y), fmaxf(p3.z, p3.w))));
        float m_ = fminf(fminf(fminf(n0.x, n0.y), fminf(n0.z, n0.w)),
                         fminf(fminf(n1.x, n1.y), fminf(n1.z, n1.w)));
        m_ = fminf(m_, fminf(fminf(fminf(n2.x, n2.y), fminf(n2.z, n2.w)),
                             fminf(fminf(n3.x, n3.y), fminf(n3.z, n3.w))));
        M = fmaxf(M, __shfl_xor(M, 1));
        m_ = fminf(m_, __shfl_xor(m_, 1));
        if (hf == 0) {
            pmp[(size_t)by * 4096 + i0 + row] = M;
            pmn[(size_t)by * 4096 + i0 + row] = m_;
        }
    }
    // transposed store: rows j of block by, reduced over cols i -> slot bx
    if (tid < 128) {
        const float4* P = (const float4*)&sm.f.mpc[tid][0];
        const float4* N = (const float4*)&sm.f.mnc[tid][0];
        float4 p0 = P[0], p1 = P[1];
        float4 n0 = N[0], n1 = N[1];
        float M = fmaxf(fmaxf(fmaxf(p0.x, p0.y), fmaxf(p0.z, p0.w)),
                        fmaxf(fmaxf(p1.x, p1.y), fmaxf(p1.z, p1.w)));
        float m_ = fminf(fminf(fminf(n0.x, n0.y), fminf(n0.z, n0.w)),
                         fminf(fminf(n1.x, n1.y), fminf(n1.z, n1.w)));
        pmp[(size_t)bx * 4096 + j0 + tid] = M;
        pmn[(size_t)bx * 4096 + j0 + tid] = m_;
    }

    // hosted diagonal tile: mine + fold (reuses sm.f.mp/mn) + store slot dslot
    if (hasdiag) {
        int ldr[4][4], ldc[4];
        float sdc[4];
#pragma unroll
        for (int ti = 0; ti < 4; ++ti) {
            int cb = dbase + wr * 64 + ti * 16 + q * 4;
            int4 lv = *(const int4*)&labels[cb];
            ldr[ti][0] = lv.x; ldr[ti][1] = lv.y; ldr[ti][2] = lv.z; ldr[ti][3] = lv.w;
        }
#pragma unroll
        for (int tj = 0; tj < 4; ++tj) {
            int cd = dbase + wc * 64 + tj * 16 + r16;
            ldc[tj] = labels[cd];
            sdc[tj] = sqn[cd];
        }
        float mpd[4][4], mnd[4][4];
#pragma unroll
        for (int ti = 0; ti < 4; ++ti)
#pragma unroll
            for (int p = 0; p < 4; ++p) { mpd[ti][p] = NEG_BIG; mnd[ti][p] = POS_BIG; }
#pragma unroll
        for (int tj = 0; tj < 4; ++tj) {
#pragma unroll
            for (int ti = 0; ti < 4; ++ti)
#pragma unroll
                for (int p = 0; p < 4; ++p) {
                    float g = accd[ti][tj][p];
                    float v = fmaf(-2.0f, g, sdc[tj]);
                    bool same = (ldr[ti][p] == ldc[tj]);
                    bool self = (wr * 64 + ti * 16 + q * 4 + p) ==
                                (wc * 64 + tj * 16 + r16);
                    mpd[ti][p] = fmaxf(mpd[ti][p], (same && !self) ? v : NEG_BIG);
                    mnd[ti][p] = fminf(mnd[ti][p], same ? POS_BIG : v);
                }
        }
        __syncthreads();  // prior folds' LDS reads done before overwrite
#pragma unroll
        for (int ti = 0; ti < 4; ++ti)
#pragma unroll
            for (int p = 0; p < 4; ++p) {
                int rloc = wr * 64 + ti * 16 + q * 4 + p;
                sm.f.mp[rloc][wc * 16 + r16] = mpd[ti][p];
                sm.f.mn[rloc][wc * 16 + r16] = mnd[ti][p];
            }
        __syncthreads();
        int row = tid >> 1, hf = tid & 1;
        const float4* P = (const float4*)&sm.f.mp[row][hf * 16];
        const float4* N = (const float4*)&sm.f.mn[row][hf * 16];
        float4 p0 = P[0], p1 = P[1], p2 = P[2], p3 = P[3];
        float4 n0 = N[0], n1 = N[1], n2 = N[2], n3 = N[3];
        float M = fmaxf(fmaxf(fmaxf(p0.x, p0.y), fmaxf(p0.z, p0.w)),
                        fmaxf(fmaxf(p1.x, p1.y), fmaxf(p1.z, p1.w)));
        M = fmaxf(M, fmaxf(fmaxf(fmaxf(p2.x, p2.y), fmaxf(p2.z, p2.w)),
                           fmaxf(fmaxf(p3.x, p3.y), fmaxf(p3.z, p3.w))));
        float m_ = fminf(fminf(fminf(n0.x, n0.y), fminf(n0.z, n0.w)),
                         fminf(fminf(n1.x, n1.y), fminf(n1.z, n1.w)));
        m_ = fminf(m_, fminf(fminf(fminf(n2.x, n2.y), fminf(n2.z, n2.w)),
                             fminf(fminf(n3.x, n3.y), fminf(n3.z, n3.w))));
        M = fmaxf(M, __shfl_xor(M, 1));
        m_ = fminf(m_, __shfl_xor(m_, 1));
        if (hf == 0) {
            pmp[(size_t)dslot * 4096 + dbase + row] = M;
            pmn[(size_t)dslot * 4096 + dbase + row] = m_;
        }
    }
}

// grid 16 x 256: fold 32 partials/row, validity via LDS label hist,
// ticket-counter finalize.
__global__ __launch_bounds__(256) void tl_phase2(const int* __restrict__ labels,
                                                 const float* __restrict__ pmp,
                                                 const float* __restrict__ pmn,
                                                 const float* __restrict__ sqn,
                                                 float* __restrict__ accum,
                                                 float* __restrict__ out) {
    __shared__ unsigned hist[256];
    __shared__ float sp[4], sv[4];
    int tid = threadIdx.x;
    hist[tid] = 0u;
    __syncthreads();
#pragma unroll
    for (int k = 0; k < 16; ++k) atomicAdd(&hist[labels[k * 256 + tid]], 1u);
    __syncthreads();

    int r = blockIdx.x * 256 + tid;
    float mp = NEG_BIG, mn = POS_BIG;
#pragma unroll
    for (int k = 0; k < 32; ++k) {
        mp = fmaxf(mp, pmp[(size_t)k * 4096 + r]);
        mn = fminf(mn, pmn[(size_t)k * 4096 + r]);
    }
    float si = sqn[r];
    unsigned cnt = hist[labels[r]];
    bool valid = (cnt >= 2u) && (cnt < 4096u);
    float hp = sqrtf(fmaxf(si + mp, 0.0f));
    float hn = sqrtf(fmaxf(si + mn, 0.0f));
    float pr = fmaxf(hp - hn + MARGIN_F, 0.0f);
    float s = valid ? pr : 0.0f;
    float n = valid ? 1.0f : 0.0f;
#pragma unroll
    for (int m = 1; m < 64; m <<= 1) {
        s += __shfl_xor(s, m);
        n += __shfl_xor(n, m);
    }
    if ((tid & 63) == 0) { sp[tid >> 6] = s; sv[tid >> 6] = n; }
    __syncthreads();
    if (tid == 0) {
        float ts = sp[0] + sp[1] + sp[2] + sp[3];
        float tn = sv[0] + sv[1] + sv[2] + sv[3];
        atomicAdd(&accum[0], ts);
        atomicAdd(&accum[1], tn);
        __threadfence();
        unsigned tk = atomicAdd((unsigned*)&accum[2], 1u);
        if (tk == 15u) {
            float a = atomicAdd(&accum[0], 0.0f);
            float b = atomicAdd(&accum[1], 0.0f);
            out[0] = a / fmaxf(b, 1.0f);
        }
    }
}

extern "C" void kernel_launch(void* const* d_in, const int* in_sizes, int n_in,
                              void* d_out, int out_size, void* d_ws, size_t ws_size,
                              hipStream_t stream) {
    const float* E = (const float*)d_in[0];
    const int* labels = (const int*)d_in[1];
    float* out = (float*)d_out;

    // ws: Ebf 1 MB | pmp 512 KB | pmn 512 KB | sqn 16 KB | accum
    char* base = (char*)d_ws;
    unsigned short* Ebf = (unsigned short*)base;
    float* pmp = (float*)(base + (1u << 20));
    float* pmn = (float*)(base + (1u << 20) + (512u << 10));
    float* sqn = (float*)(base + (2u << 20));
    float* accum = (float*)(base + (2u << 20) + (16u << 10));

    tl_prep<<<512, 256, 0, stream>>>(E, Ebf, sqn, (unsigned*)accum);
    tl_phase1<<<496, 256, 0, stream>>>(Ebf, labels, sqn, pmp, pmn);
    tl_phase2<<<16, 256, 0, stream>>>(labels, pmp, pmn, sqn, accum, out);
}